// Round 7
// baseline (901.517 us; speedup 1.0000x reference)
//
#include <hip/hip_runtime.h>

#define NROWS 32768   // B*T
#define PD    512     // P_DIM
#define NCB   8       // NC
#define CSZ   256     // CS
#define TOTD  2048    // TOT
#define SIN   1792    // SELF_IN / SELF_OUT

typedef float  floatx4  __attribute__((ext_vector_type(4)));
typedef __bf16 bf16x8_t __attribute__((ext_vector_type(8)));

__device__ __forceinline__ unsigned short f2bf(float f) {
    unsigned int u = __float_as_uint(f);
    u += 0x7FFFu + ((u >> 16) & 1u);     // round-to-nearest-even
    return (unsigned short)(u >> 16);
}
__device__ __forceinline__ float bf2f(unsigned int h) {
    return __uint_as_float(h << 16);
}

// async global->LDS, 16B per lane; LDS dest = wave-uniform base + lane*16
__device__ __forceinline__ void gload16(const unsigned short* g, unsigned short* l) {
    __builtin_amdgcn_global_load_lds(
        (const __attribute__((address_space(1))) void*)g,
        (__attribute__((address_space(3))) void*)l, 16, 0, 0);
}

// ---------------- f32 -> bf16 conversion (vectorized) ----------------
__global__ __launch_bounds__(256) void k_cvt(const float* __restrict__ in,
                                             unsigned short* __restrict__ out,
                                             int n4) {
    int i = blockIdx.x * 256 + threadIdx.x;
    if (i >= n4) return;
    float4 v = ((const float4*)in)[i];
    ushort4 o;
    o.x = f2bf(v.x); o.y = f2bf(v.y); o.z = f2bf(v.z); o.w = f2bf(v.w);
    ((ushort4*)out)[i] = o;
}

// -------- transpose linear_self (1792x1792) f32 -> bf16, LSTb[in][out] --------
__global__ __launch_bounds__(256) void k_tb(const float* __restrict__ in,
                                            unsigned short* __restrict__ out) {
    __shared__ float t[32][33];
    int bx = blockIdx.x * 32, by = blockIdx.y * 32;
    int tx = threadIdx.x & 31, ty = threadIdx.x >> 5;   // 32 x 8
#pragma unroll
    for (int j = 0; j < 32; j += 8)
        t[ty + j][tx] = in[(size_t)(by + ty + j) * SIN + bx + tx];
    __syncthreads();
#pragma unroll
    for (int j = 0; j < 32; j += 8)
        out[(size_t)(bx + ty + j) * SIN + by + tx] = f2bf(t[tx][ty + j]);
}

// ---------------- GEMM1: Hraw = pred @ W1^T + b1 -> bf16 ----------------
// flat grid 4096: rb = bid & 255, cb = bid >> 8 -> col-sharers on same XCD.
__global__ __launch_bounds__(256) void k_gemm1(const unsigned short* __restrict__ A,
                                               const unsigned short* __restrict__ Bw,
                                               const float* __restrict__ bias,
                                               unsigned short* __restrict__ Out) {
    const int K = PD;
    __shared__ __align__(16) unsigned short As[128 * 32];
    __shared__ __align__(16) unsigned short Bs[128 * 32];

    const int tid  = threadIdx.x;
    const int lane = tid & 63;
    const int wave = tid >> 6;
    const int wm = (wave >> 1) << 6;
    const int wn = (wave & 1) << 6;
    const int bid  = blockIdx.x;
    const int row0 = (bid & 255) << 7;
    const int col0 = (bid >> 8) << 7;

    floatx4 acc[4][4] = {};

    const int lm = lane & 15, lq = lane >> 4;
    const size_t aoff = (size_t)(row0 + wave * 16 + lm) * K + lq * 8;
    const size_t boff = (size_t)(col0 + wave * 16 + lm) * K + lq * 8;
    unsigned short* AsW0 = As + wave * 512;
    unsigned short* AsW1 = As + (wave + 4) * 512;
    unsigned short* BsW0 = Bs + wave * 512;
    unsigned short* BsW1 = Bs + (wave + 4) * 512;

    for (int k0 = 0; k0 < K; k0 += 32) {
        gload16(A  + aoff + k0, AsW0);
        gload16(A  + aoff + (size_t)64 * K + k0, AsW1);
        gload16(Bw + boff + k0, BsW0);
        gload16(Bw + boff + (size_t)64 * K + k0, BsW1);
        __syncthreads();

        bf16x8_t af[4], bfr[4];
        const bf16x8_t* Ap = (const bf16x8_t*)As;
        const bf16x8_t* Bp = (const bf16x8_t*)Bs;
#pragma unroll
        for (int mt = 0; mt < 4; ++mt) af[mt] = Ap[((wm >> 4) + mt) * 64 + lane];
#pragma unroll
        for (int nt = 0; nt < 4; ++nt) bfr[nt] = Bp[((wn >> 4) + nt) * 64 + lane];
#pragma unroll
        for (int mt = 0; mt < 4; ++mt)
#pragma unroll
            for (int nt = 0; nt < 4; ++nt)
                acc[mt][nt] = __builtin_amdgcn_mfma_f32_16x16x32_bf16(af[mt], bfr[nt], acc[mt][nt], 0, 0, 0);
        __syncthreads();
    }

#pragma unroll
    for (int mt = 0; mt < 4; ++mt) {
        const int rowb = row0 + wm + mt * 16 + ((lane >> 4) << 2);
#pragma unroll
        for (int nt = 0; nt < 4; ++nt) {
            const int col = col0 + wn + nt * 16 + (lane & 15);
            const float bcol = bias[col];
#pragma unroll
            for (int r = 0; r < 4; ++r)
                Out[(size_t)(rowb + r) * TOTD + col] = f2bf(acc[mt][nt][r] + bcol);
        }
    }
}

// -------- fused: self-gather + relu + LayerNorm (in place, bf16), 1 row/block --------
__global__ __launch_bounds__(256) void k_ln(unsigned short* __restrict__ H,
                                            const unsigned short* __restrict__ LSTb,
                                            const int* __restrict__ idx,
                                            const float* __restrict__ gamma,
                                            const float* __restrict__ beta) {
    const int row = blockIdx.x;
    const int tid = threadIdx.x;
    __shared__ int sidx[8];
    __shared__ float ws4[4], wss4[4];
    if (tid < 8) sidx[tid] = idx[(size_t)row * NCB + tid];

    unsigned short* rp = H + (size_t)row * TOTD;
    uint4 raw = ((const uint4*)rp)[tid];
    float x[8];
    x[0] = bf2f(raw.x & 0xFFFF); x[1] = bf2f(raw.x >> 16);
    x[2] = bf2f(raw.y & 0xFFFF); x[3] = bf2f(raw.y >> 16);
    x[4] = bf2f(raw.z & 0xFFFF); x[5] = bf2f(raw.z >> 16);
    x[6] = bf2f(raw.w & 0xFFFF); x[7] = bf2f(raw.w >> 16);
    __syncthreads();

    const int gt = tid >> 5;
#pragma unroll
    for (int c = 0; c < 7; ++c) {
        if (c < gt) {
            int ic = sidx[c];
            if (ic >= 0) {
                uint4 v = *(const uint4*)(LSTb + (size_t)(c * CSZ + ic) * SIN + (tid * 8 - CSZ));
                x[0] += bf2f(v.x & 0xFFFF); x[1] += bf2f(v.x >> 16);
                x[2] += bf2f(v.y & 0xFFFF); x[3] += bf2f(v.y >> 16);
                x[4] += bf2f(v.z & 0xFFFF); x[5] += bf2f(v.z >> 16);
                x[6] += bf2f(v.w & 0xFFFF); x[7] += bf2f(v.w >> 16);
            }
        }
    }
#pragma unroll
    for (int e = 0; e < 8; ++e) x[e] = fmaxf(x[e], 0.f);

    float s = 0.f, ss = 0.f;
#pragma unroll
    for (int e = 0; e < 8; ++e) { s += x[e]; ss += x[e] * x[e]; }
#pragma unroll
    for (int o = 32; o; o >>= 1) { s += __shfl_xor(s, o); ss += __shfl_xor(ss, o); }
    if ((tid & 63) == 0) { ws4[tid >> 6] = s; wss4[tid >> 6] = ss; }
    __syncthreads();
    s  = ws4[0] + ws4[1] + ws4[2] + ws4[3];
    ss = wss4[0] + wss4[1] + wss4[2] + wss4[3];
    const float mu = s * (1.f / TOTD);
    const float var = ss * (1.f / TOTD) - mu * mu;
    const float rstd = rsqrtf(var + 1e-5f);
    unsigned int o32[4];
#pragma unroll
    for (int p = 0; p < 4; ++p) {
        int col = tid * 8 + p * 2;
        float y0 = (x[p * 2] - mu) * rstd * gamma[col] + beta[col];
        float y1 = (x[p * 2 + 1] - mu) * rstd * gamma[col + 1] + beta[col + 1];
        o32[p] = (unsigned int)f2bf(y0) | ((unsigned int)f2bf(y1) << 16);
    }
    uint4 o; o.x = o32[0]; o.y = o32[1]; o.z = o32[2]; o.w = o32[3];
    ((uint4*)rp)[tid] = o;
}

// ------- GEMM2: plain 128x128 m97-shape tile + per-row partial-softmax epilogue -------
// flat grid 4096: rb = bid & 255 (row-tile), cb = bid >> 8 (col-block of 128)
// => 16 col-sharers of a row-tile land on the same XCD (256 % 8 == 0).
// Epilogue: each wave owns 64 rows x 64 cols; per row emit (max, sum-exp, target-partial)
// into part arrays indexed [slot][row], slot = global_col/64 (0..31).
__global__ __launch_bounds__(256) void k_gemm2(const unsigned short* __restrict__ H,
                                               const unsigned short* __restrict__ W2,
                                               const float* __restrict__ b2,
                                               const int* __restrict__ idx,
                                               float* __restrict__ pm_,
                                               float* __restrict__ ps_,
                                               float* __restrict__ pt_) {
    const int K = TOTD;
    __shared__ __align__(16) unsigned short As[128 * 32];
    __shared__ __align__(16) unsigned short Bs[128 * 32];
    __shared__ int tidx[128];

    const int tid  = threadIdx.x;
    const int lane = tid & 63;
    const int wave = tid >> 6;
    const int wm = (wave >> 1) << 6;
    const int wn = (wave & 1) << 6;
    const int bid  = blockIdx.x;
    const int row0 = (bid & 255) << 7;
    const int col0 = (bid >> 8) << 7;
    const int g    = col0 >> 8;          // codebook group of this col-block

    floatx4 acc[4][4] = {};

    const int lm = lane & 15, lq = lane >> 4;
    const size_t aoff = (size_t)(row0 + wave * 16 + lm) * K + lq * 8;
    const size_t boff = (size_t)(col0 + wave * 16 + lm) * K + lq * 8;
    unsigned short* AsW0 = As + wave * 512;
    unsigned short* AsW1 = As + (wave + 4) * 512;
    unsigned short* BsW0 = Bs + wave * 512;
    unsigned short* BsW1 = Bs + (wave + 4) * 512;

    if (tid < 128) tidx[tid] = idx[(size_t)(row0 + tid) * NCB + g];

    for (int k0 = 0; k0 < K; k0 += 32) {
        gload16(H  + aoff + k0, AsW0);
        gload16(H  + aoff + (size_t)64 * K + k0, AsW1);
        gload16(W2 + boff + k0, BsW0);
        gload16(W2 + boff + (size_t)64 * K + k0, BsW1);
        __syncthreads();

        bf16x8_t af[4], bfr[4];
        const bf16x8_t* Ap = (const bf16x8_t*)As;
        const bf16x8_t* Bp = (const bf16x8_t*)Bs;
#pragma unroll
        for (int mt = 0; mt < 4; ++mt) af[mt] = Ap[((wm >> 4) + mt) * 64 + lane];
#pragma unroll
        for (int nt = 0; nt < 4; ++nt) bfr[nt] = Bp[((wn >> 4) + nt) * 64 + lane];
#pragma unroll
        for (int mt = 0; mt < 4; ++mt)
#pragma unroll
            for (int nt = 0; nt < 4; ++nt)
                acc[mt][nt] = __builtin_amdgcn_mfma_f32_16x16x32_bf16(af[mt], bfr[nt], acc[mt][nt], 0, 0, 0);
        __syncthreads();
    }

    // ---- epilogue: per-row partials over this wave's 64-col window ----
    const int rl = (lane >> 4) << 2;     // row base within 16-tile
    const int cl = lane & 15;            // col within 16-tile
    const int slot = (col0 + wn) >> 6;   // 0..31
    const int coff = (col0 & 255) + wn;  // window start within the 256-col group
    float bcol[4];
#pragma unroll
    for (int nt = 0; nt < 4; ++nt) bcol[nt] = b2[col0 + wn + nt * 16 + cl];

#pragma unroll
    for (int mt = 0; mt < 4; ++mt) {
#pragma unroll
        for (int r = 0; r < 4; ++r) {
            const int lrow = wm + mt * 16 + rl + r;     // local row 0..127
            const int ic   = tidx[lrow];
            const int tloc = ic - coff;                 // target col within window, if 0..63
            float v[4];
            float mm = -3.4e38f, tv = 0.f;
#pragma unroll
            for (int nt = 0; nt < 4; ++nt) {
                v[nt] = acc[mt][nt][r] + bcol[nt];
                mm = fmaxf(mm, v[nt]);
                if (ic >= 0 && (nt * 16 + cl) == tloc) tv += v[nt];
            }
#pragma unroll
            for (int o = 1; o < 16; o <<= 1) mm = fmaxf(mm, __shfl_xor(mm, o));
            float sv = __expf(v[0] - mm) + __expf(v[1] - mm) + __expf(v[2] - mm) + __expf(v[3] - mm);
#pragma unroll
            for (int o = 1; o < 16; o <<= 1) { sv += __shfl_xor(sv, o); tv += __shfl_xor(tv, o); }
            if (cl == 0) {
                const int row = row0 + lrow;
                pm_[(size_t)slot * NROWS + row] = mm;
                ps_[(size_t)slot * NROWS + row] = sv;
                pt_[(size_t)slot * NROWS + row] = tv;
            }
        }
    }
}

// ------- combine: merge 4 slots per (row, group), accumulate logprob + count -------
__global__ __launch_bounds__(256) void k_comb(const float* __restrict__ pm_,
                                              const float* __restrict__ ps_,
                                              const float* __restrict__ pt_,
                                              const int* __restrict__ idx,
                                              float* __restrict__ out) {
    const int i   = blockIdx.x * 256 + threadIdx.x;   // [0, 8*32768)
    const int row = i & (NROWS - 1);
    const int g   = i >> 15;
    const int ic  = idx[(size_t)row * NCB + g];
    float lp = 0.f, cnt = 0.f;
    if (ic >= 0) {
        const size_t b = (size_t)(g * 4) * NROWS + row;
        float m0 = pm_[b], m1 = pm_[b + NROWS], m2 = pm_[b + 2 * NROWS], m3 = pm_[b + 3 * NROWS];
        float mm = fmaxf(fmaxf(m0, m1), fmaxf(m2, m3));
        float Z = ps_[b] * __expf(m0 - mm) + ps_[b + NROWS] * __expf(m1 - mm)
                + ps_[b + 2 * NROWS] * __expf(m2 - mm) + ps_[b + 3 * NROWS] * __expf(m3 - mm);
        float t = pt_[b] + pt_[b + NROWS] + pt_[b + 2 * NROWS] + pt_[b + 3 * NROWS];
        lp = t - (mm + __logf(Z));
        cnt = 1.f;
    }
#pragma unroll
    for (int o = 1; o < 64; o <<= 1) { lp += __shfl_xor(lp, o); cnt += __shfl_xor(cnt, o); }
    __shared__ float wred[8];
    const int lane = threadIdx.x & 63, wave = threadIdx.x >> 6;
    if (lane == 0) { wred[wave] = lp; wred[4 + wave] = cnt; }
    __syncthreads();
    if (threadIdx.x == 0) {
        atomicAdd(&out[0], wred[0] + wred[1] + wred[2] + wred[3]);
        atomicAdd(&out[1], wred[4] + wred[5] + wred[6] + wred[7]);
    }
}

extern "C" void kernel_launch(void* const* d_in, const int* in_sizes, int n_in,
                              void* d_out, int out_size, void* d_ws, size_t ws_size,
                              hipStream_t stream) {
    const float* predictor = (const float*)d_in[0];
    const int*   cbidx     = (const int*)d_in[1];
    const float* W1        = (const float*)d_in[2];
    const float* b1        = (const float*)d_in[3];
    const float* LS        = (const float*)d_in[4];
    const float* gamma     = (const float*)d_in[5];
    const float* beta      = (const float*)d_in[6];
    const float* W2        = (const float*)d_in[7];
    const float* b2        = (const float*)d_in[8];
    float* out = (float*)d_out;

    char* ws = (char*)d_ws;
    size_t off = 0;
    auto alloc = [&](size_t bytes) {
        char* p = ws + off;
        off += (bytes + 255) & ~(size_t)255;
        return p;
    };
    unsigned short* pred16 = (unsigned short*)alloc((size_t)NROWS * PD * 2);   // 33.6 MB
    unsigned short* W1_16  = (unsigned short*)alloc((size_t)TOTD * PD * 2);    //  2.1 MB
    unsigned short* W2_16  = (unsigned short*)alloc((size_t)TOTD * TOTD * 2);  //  8.4 MB
    unsigned short* LSTb   = (unsigned short*)alloc((size_t)SIN * SIN * 2);    //  6.4 MB
    unsigned short* Hbuf   = (unsigned short*)alloc((size_t)NROWS * TOTD * 2); // 134.2 MB
    float*          pm_    = (float*)alloc((size_t)32 * NROWS * 4);            //  4.2 MB
    float*          ps_    = (float*)alloc((size_t)32 * NROWS * 4);            //  4.2 MB
    float*          pt_    = (float*)alloc((size_t)32 * NROWS * 4);            //  4.2 MB

    hipMemsetAsync(d_out, 0, 2 * sizeof(float), stream);

    k_cvt<<<NROWS * PD / 4 / 256, 256, 0, stream>>>(predictor, pred16, NROWS * PD / 4);
    k_cvt<<<TOTD * PD / 4 / 256, 256, 0, stream>>>(W1, W1_16, TOTD * PD / 4);
    k_cvt<<<TOTD * TOTD / 4 / 256, 256, 0, stream>>>(W2, W2_16, TOTD * TOTD / 4);
    k_tb<<<dim3(SIN / 32, SIN / 32), 256, 0, stream>>>(LS, LSTb);

    k_gemm1<<<16 * 256, 256, 0, stream>>>(pred16, W1_16, b1, Hbuf);
    k_ln<<<NROWS, 256, 0, stream>>>(Hbuf, LSTb, cbidx, gamma, beta);
    k_gemm2<<<16 * 256, 256, 0, stream>>>(Hbuf, W2_16, b2, cbidx, pm_, ps_, pt_);
    k_comb<<<NROWS * NCB / 256, 256, 0, stream>>>(pm_, ps_, pt_, cbidx, out);
}

// Round 8
// 697.057 us; speedup vs baseline: 1.2933x; 1.2933x over previous
//
#include <hip/hip_runtime.h>

#define NROWS 32768   // B*T
#define PD    512     // P_DIM
#define NCB   8       // NC
#define CSZ   256     // CS
#define TOTD  2048    // TOT
#define SIN   1792    // SELF_IN / SELF_OUT

typedef float floatx4 __attribute__((ext_vector_type(4)));

__device__ __forceinline__ float bf2f(unsigned int h) {
    return __uint_as_float(h << 16);
}
__device__ __forceinline__ unsigned short f2bf(float f) {
    unsigned int u = __float_as_uint(f);
    u += 0x7FFFu + ((u >> 16) & 1u);
    return (unsigned short)(u >> 16);
}
// f32 -> fp8 e4m3 (single value, RNE, saturating)
__device__ __forceinline__ unsigned char f2fp8(float v) {
    int p = __builtin_amdgcn_cvt_pk_fp8_f32(v, v, 0, false);
    return (unsigned char)(p & 0xFF);
}

// async global->LDS, 16B per lane; LDS dest = wave-uniform base + lane*16
__device__ __forceinline__ void gload16(const unsigned char* g, unsigned char* l) {
    __builtin_amdgcn_global_load_lds(
        (const __attribute__((address_space(1))) void*)g,
        (__attribute__((address_space(3))) void*)l, 16, 0, 0);
}

// ---------------- f32 -> fp8 conversion (8 elems/thread) ----------------
__global__ __launch_bounds__(256) void k_cvt8(const float* __restrict__ in,
                                              unsigned char* __restrict__ out,
                                              float scale, int n8) {
    int i = blockIdx.x * 256 + threadIdx.x;
    if (i >= n8) return;
    float4 a = ((const float4*)in)[2 * i];
    float4 b = ((const float4*)in)[2 * i + 1];
    int p0 = __builtin_amdgcn_cvt_pk_fp8_f32(a.x * scale, a.y * scale, 0, false);
    p0     = __builtin_amdgcn_cvt_pk_fp8_f32(a.z * scale, a.w * scale, p0, true);
    int p1 = __builtin_amdgcn_cvt_pk_fp8_f32(b.x * scale, b.y * scale, 0, false);
    p1     = __builtin_amdgcn_cvt_pk_fp8_f32(b.z * scale, b.w * scale, p1, true);
    int2 o; o.x = p0; o.y = p1;
    ((int2*)out)[i] = o;
}

// -------- transpose linear_self (1792x1792) f32 -> bf16, LSTb[in][out] --------
__global__ __launch_bounds__(256) void k_tb(const float* __restrict__ in,
                                            unsigned short* __restrict__ out) {
    __shared__ float t[32][33];
    int bx = blockIdx.x * 32, by = blockIdx.y * 32;
    int tx = threadIdx.x & 31, ty = threadIdx.x >> 5;
#pragma unroll
    for (int j = 0; j < 32; j += 8)
        t[ty + j][tx] = in[(size_t)(by + ty + j) * SIN + bx + tx];
    __syncthreads();
#pragma unroll
    for (int j = 0; j < 32; j += 8)
        out[(size_t)(bx + ty + j) * SIN + by + tx] = f2bf(t[tx][ty + j]);
}

// ---------------- GEMM1 (fp8): Hraw8 = fp8(8 * (pred @ W1^T + b1)) ----------------
// A scale 1, B scale 16 -> hidden = acc/16 + b1. flat grid 4096 (rb=bid&255).
// K-loop: BK=64 (2x32 slabs), double-buffered LDS, prefetch issued AFTER barrier.
__global__ __launch_bounds__(256) void k_gemm1(const unsigned char* __restrict__ A,
                                               const unsigned char* __restrict__ Bw,
                                               const float* __restrict__ bias,
                                               unsigned char* __restrict__ Out) {
    const int K = PD;
    __shared__ __align__(16) unsigned char As[2 * 8192];
    __shared__ __align__(16) unsigned char Bs[2 * 8192];

    const int tid  = threadIdx.x;
    const int lane = tid & 63;
    const int wave = tid >> 6;
    const int wm = (wave >> 1) << 6;
    const int wn = (wave & 1) << 6;
    const int bid  = blockIdx.x;
    const int row0 = (bid & 255) << 7;
    const int col0 = (bid >> 8) << 7;

    floatx4 acc[4][4] = {};

    // staging: lane i covers row wave*32 + (i>>1), k bytes (i&1)*16..+15 of each 32-k slab
    const unsigned char* Ag = A  + (size_t)(row0 + wave * 32 + (lane >> 1)) * K + (lane & 1) * 16;
    const unsigned char* Bg = Bw + (size_t)(col0 + wave * 32 + (lane >> 1)) * K + (lane & 1) * 16;
    unsigned char* Al = As + wave * 1024;
    unsigned char* Bl = Bs + wave * 1024;

    gload16(Ag,      Al);
    gload16(Ag + 32, Al + 4096);
    gload16(Bg,      Bl);
    gload16(Bg + 32, Bl + 4096);

    const int NI = K / 64;   // 8
    for (int i = 0; i < NI; ++i) {
        const int cur = (i & 1) << 13;
        __syncthreads();                 // drains only THIS iter's loads (prefetch not yet issued)
        if (i + 1 < NI) {
            const int nb = ((i + 1) & 1) << 13;
            const int k0 = (i + 1) * 64;
            gload16(Ag + k0,      Al + nb);
            gload16(Ag + k0 + 32, Al + nb + 4096);
            gload16(Bg + k0,      Bl + nb);
            gload16(Bg + k0 + 32, Bl + nb + 4096);
        }
        const int fo = ((lane & 15) * 4 + (lane >> 4)) * 8;   // chunk = m*4 + q
#pragma unroll
        for (int s = 0; s < 2; ++s) {
            const unsigned char* Ab = As + cur + s * 4096 + fo;
            const unsigned char* Bb = Bs + cur + s * 4096 + fo;
            long af[4], bfv[4];
#pragma unroll
            for (int mt = 0; mt < 4; ++mt) af[mt]  = *(const long*)(Ab + ((wm >> 4) + mt) * 512);
#pragma unroll
            for (int nt = 0; nt < 4; ++nt) bfv[nt] = *(const long*)(Bb + ((wn >> 4) + nt) * 512);
#pragma unroll
            for (int mt = 0; mt < 4; ++mt)
#pragma unroll
                for (int nt = 0; nt < 4; ++nt)
                    acc[mt][nt] = __builtin_amdgcn_mfma_f32_16x16x32_fp8_fp8(af[mt], bfv[nt], acc[mt][nt], 0, 0, 0);
        }
    }

    // epilogue: hidden = acc/16 + b1; store fp8(8*hidden)
#pragma unroll
    for (int mt = 0; mt < 4; ++mt) {
        const int rowb = row0 + wm + mt * 16 + ((lane >> 4) << 2);
#pragma unroll
        for (int nt = 0; nt < 4; ++nt) {
            const int col = col0 + wn + nt * 16 + (lane & 15);
            const float bcol = bias[col];
#pragma unroll
            for (int r = 0; r < 4; ++r) {
                float h = acc[mt][nt][r] * 0.0625f + bcol;
                Out[(size_t)(rowb + r) * TOTD + col] = f2fp8(h * 8.f);
            }
        }
    }
}

// -------- fused: self-gather + relu + LayerNorm; fp8 in (x8) -> fp8 out (x8) --------
__global__ __launch_bounds__(256) void k_ln(const unsigned char* __restrict__ Hraw8,
                                            unsigned char* __restrict__ H8,
                                            const unsigned short* __restrict__ LSTb,
                                            const int* __restrict__ idx,
                                            const float* __restrict__ gamma,
                                            const float* __restrict__ beta) {
    const int row = blockIdx.x;
    const int tid = threadIdx.x;
    __shared__ int sidx[8];
    __shared__ float ws4[4], wss4[4];
    if (tid < 8) sidx[tid] = idx[(size_t)row * NCB + tid];

    uint2 w = ((const uint2*)(Hraw8 + (size_t)row * TOTD))[tid];
    float x[8];
    x[0] = __builtin_amdgcn_cvt_f32_fp8(w.x, 0) * 0.125f;
    x[1] = __builtin_amdgcn_cvt_f32_fp8(w.x, 1) * 0.125f;
    x[2] = __builtin_amdgcn_cvt_f32_fp8(w.x, 2) * 0.125f;
    x[3] = __builtin_amdgcn_cvt_f32_fp8(w.x, 3) * 0.125f;
    x[4] = __builtin_amdgcn_cvt_f32_fp8(w.y, 0) * 0.125f;
    x[5] = __builtin_amdgcn_cvt_f32_fp8(w.y, 1) * 0.125f;
    x[6] = __builtin_amdgcn_cvt_f32_fp8(w.y, 2) * 0.125f;
    x[7] = __builtin_amdgcn_cvt_f32_fp8(w.y, 3) * 0.125f;
    __syncthreads();

    const int gt = tid >> 5;
#pragma unroll
    for (int c = 0; c < 7; ++c) {
        if (c < gt) {
            int ic = sidx[c];
            if (ic >= 0) {
                uint4 v = *(const uint4*)(LSTb + (size_t)(c * CSZ + ic) * SIN + (tid * 8 - CSZ));
                x[0] += bf2f(v.x & 0xFFFF); x[1] += bf2f(v.x >> 16);
                x[2] += bf2f(v.y & 0xFFFF); x[3] += bf2f(v.y >> 16);
                x[4] += bf2f(v.z & 0xFFFF); x[5] += bf2f(v.z >> 16);
                x[6] += bf2f(v.w & 0xFFFF); x[7] += bf2f(v.w >> 16);
            }
        }
    }
#pragma unroll
    for (int e = 0; e < 8; ++e) x[e] = fmaxf(x[e], 0.f);

    float s = 0.f, ss = 0.f;
#pragma unroll
    for (int e = 0; e < 8; ++e) { s += x[e]; ss += x[e] * x[e]; }
#pragma unroll
    for (int o = 32; o; o >>= 1) { s += __shfl_xor(s, o); ss += __shfl_xor(ss, o); }
    if ((tid & 63) == 0) { ws4[tid >> 6] = s; wss4[tid >> 6] = ss; }
    __syncthreads();
    s  = ws4[0] + ws4[1] + ws4[2] + ws4[3];
    ss = wss4[0] + wss4[1] + wss4[2] + wss4[3];
    const float mu = s * (1.f / TOTD);
    const float var = ss * (1.f / TOTD) - mu * mu;
    const float rstd = rsqrtf(var + 1e-5f);
    float y[8];
#pragma unroll
    for (int e = 0; e < 8; ++e) {
        int col = tid * 8 + e;
        y[e] = ((x[e] - mu) * rstd * gamma[col] + beta[col]) * 8.f;   // H scale 8
    }
    int p0 = __builtin_amdgcn_cvt_pk_fp8_f32(y[0], y[1], 0, false);
    p0     = __builtin_amdgcn_cvt_pk_fp8_f32(y[2], y[3], p0, true);
    int p1 = __builtin_amdgcn_cvt_pk_fp8_f32(y[4], y[5], 0, false);
    p1     = __builtin_amdgcn_cvt_pk_fp8_f32(y[6], y[7], p1, true);
    int2 o; o.x = p0; o.y = p1;
    ((int2*)(H8 + (size_t)row * TOTD))[tid] = o;
}

// ------- GEMM2 (fp8): 128x128 tile, dbuf pipeline + per-row partial-softmax epilogue -------
// A scale 8, B scale 16 -> logits = acc/128 + b2. flat grid 4096 (rb=bid&255).
__global__ __launch_bounds__(256) void k_gemm2(const unsigned char* __restrict__ H,
                                               const unsigned char* __restrict__ W2,
                                               const float* __restrict__ b2,
                                               const int* __restrict__ idx,
                                               float* __restrict__ pm_,
                                               float* __restrict__ ps_,
                                               float* __restrict__ pt_) {
    const int K = TOTD;
    __shared__ __align__(16) unsigned char As[2 * 8192];
    __shared__ __align__(16) unsigned char Bs[2 * 8192];
    __shared__ int tidx[128];

    const int tid  = threadIdx.x;
    const int lane = tid & 63;
    const int wave = tid >> 6;
    const int wm = (wave >> 1) << 6;
    const int wn = (wave & 1) << 6;
    const int bid  = blockIdx.x;
    const int row0 = (bid & 255) << 7;
    const int col0 = (bid >> 8) << 7;
    const int g    = col0 >> 8;

    floatx4 acc[4][4] = {};

    const unsigned char* Ag = H  + (size_t)(row0 + wave * 32 + (lane >> 1)) * K + (lane & 1) * 16;
    const unsigned char* Bg = W2 + (size_t)(col0 + wave * 32 + (lane >> 1)) * K + (lane & 1) * 16;
    unsigned char* Al = As + wave * 1024;
    unsigned char* Bl = Bs + wave * 1024;

    if (tid < 128) tidx[tid] = idx[(size_t)(row0 + tid) * NCB + g];

    gload16(Ag,      Al);
    gload16(Ag + 32, Al + 4096);
    gload16(Bg,      Bl);
    gload16(Bg + 32, Bl + 4096);

    const int NI = K / 64;   // 32
    for (int i = 0; i < NI; ++i) {
        const int cur = (i & 1) << 13;
        __syncthreads();
        if (i + 1 < NI) {
            const int nb = ((i + 1) & 1) << 13;
            const int k0 = (i + 1) * 64;
            gload16(Ag + k0,      Al + nb);
            gload16(Ag + k0 + 32, Al + nb + 4096);
            gload16(Bg + k0,      Bl + nb);
            gload16(Bg + k0 + 32, Bl + nb + 4096);
        }
        const int fo = ((lane & 15) * 4 + (lane >> 4)) * 8;
#pragma unroll
        for (int s = 0; s < 2; ++s) {
            const unsigned char* Ab = As + cur + s * 4096 + fo;
            const unsigned char* Bb = Bs + cur + s * 4096 + fo;
            long af[4], bfv[4];
#pragma unroll
            for (int mt = 0; mt < 4; ++mt) af[mt]  = *(const long*)(Ab + ((wm >> 4) + mt) * 512);
#pragma unroll
            for (int nt = 0; nt < 4; ++nt) bfv[nt] = *(const long*)(Bb + ((wn >> 4) + nt) * 512);
#pragma unroll
            for (int mt = 0; mt < 4; ++mt)
#pragma unroll
                for (int nt = 0; nt < 4; ++nt)
                    acc[mt][nt] = __builtin_amdgcn_mfma_f32_16x16x32_fp8_fp8(af[mt], bfv[nt], acc[mt][nt], 0, 0, 0);
        }
    }

    // ---- epilogue: per-row partials over this wave's 64-col window ----
    const int rl = (lane >> 4) << 2;
    const int cl = lane & 15;
    const int slot = (col0 + wn) >> 6;   // 0..31
    const int coff = (col0 & 255) + wn;
    float bcol[4];
#pragma unroll
    for (int nt = 0; nt < 4; ++nt) bcol[nt] = b2[col0 + wn + nt * 16 + cl];

#pragma unroll
    for (int mt = 0; mt < 4; ++mt) {
#pragma unroll
        for (int r = 0; r < 4; ++r) {
            const int lrow = wm + mt * 16 + rl + r;
            const int ic   = tidx[lrow];
            const int tloc = ic - coff;
            float v[4];
            float mm = -3.4e38f, tv = 0.f;
#pragma unroll
            for (int nt = 0; nt < 4; ++nt) {
                v[nt] = acc[mt][nt][r] * 0.0078125f + bcol[nt];
                mm = fmaxf(mm, v[nt]);
                if (ic >= 0 && (nt * 16 + cl) == tloc) tv += v[nt];
            }
#pragma unroll
            for (int o = 1; o < 16; o <<= 1) mm = fmaxf(mm, __shfl_xor(mm, o));
            float sv = __expf(v[0] - mm) + __expf(v[1] - mm) + __expf(v[2] - mm) + __expf(v[3] - mm);
#pragma unroll
            for (int o = 1; o < 16; o <<= 1) { sv += __shfl_xor(sv, o); tv += __shfl_xor(tv, o); }
            if (cl == 0) {
                const int row = row0 + lrow;
                pm_[(size_t)slot * NROWS + row] = mm;
                ps_[(size_t)slot * NROWS + row] = sv;
                pt_[(size_t)slot * NROWS + row] = tv;
            }
        }
    }
}

// ------- combine: merge 4 slots per (row, group), accumulate logprob + count -------
__global__ __launch_bounds__(256) void k_comb(const float* __restrict__ pm_,
                                              const float* __restrict__ ps_,
                                              const float* __restrict__ pt_,
                                              const int* __restrict__ idx,
                                              float* __restrict__ out) {
    const int i   = blockIdx.x * 256 + threadIdx.x;
    const int row = i & (NROWS - 1);
    const int g   = i >> 15;
    const int ic  = idx[(size_t)row * NCB + g];
    float lp = 0.f, cnt = 0.f;
    if (ic >= 0) {
        const size_t b = (size_t)(g * 4) * NROWS + row;
        float m0 = pm_[b], m1 = pm_[b + NROWS], m2 = pm_[b + 2 * NROWS], m3 = pm_[b + 3 * NROWS];
        float mm = fmaxf(fmaxf(m0, m1), fmaxf(m2, m3));
        float Z = ps_[b] * __expf(m0 - mm) + ps_[b + NROWS] * __expf(m1 - mm)
                + ps_[b + 2 * NROWS] * __expf(m2 - mm) + ps_[b + 3 * NROWS] * __expf(m3 - mm);
        float t = pt_[b] + pt_[b + NROWS] + pt_[b + 2 * NROWS] + pt_[b + 3 * NROWS];
        lp = t - (mm + __logf(Z));
        cnt = 1.f;
    }
#pragma unroll
    for (int o = 1; o < 64; o <<= 1) { lp += __shfl_xor(lp, o); cnt += __shfl_xor(cnt, o); }
    __shared__ float wred[8];
    const int lane = threadIdx.x & 63, wave = threadIdx.x >> 6;
    if (lane == 0) { wred[wave] = lp; wred[4 + wave] = cnt; }
    __syncthreads();
    if (threadIdx.x == 0) {
        atomicAdd(&out[0], wred[0] + wred[1] + wred[2] + wred[3]);
        atomicAdd(&out[1], wred[4] + wred[5] + wred[6] + wred[7]);
    }
}

extern "C" void kernel_launch(void* const* d_in, const int* in_sizes, int n_in,
                              void* d_out, int out_size, void* d_ws, size_t ws_size,
                              hipStream_t stream) {
    const float* predictor = (const float*)d_in[0];
    const int*   cbidx     = (const int*)d_in[1];
    const float* W1        = (const float*)d_in[2];
    const float* b1        = (const float*)d_in[3];
    const float* LS        = (const float*)d_in[4];
    const float* gamma     = (const float*)d_in[5];
    const float* beta      = (const float*)d_in[6];
    const float* W2        = (const float*)d_in[7];
    const float* b2        = (const float*)d_in[8];
    float* out = (float*)d_out;

    char* ws = (char*)d_ws;
    size_t off = 0;
    auto alloc = [&](size_t bytes) {
        char* p = ws + off;
        off += (bytes + 255) & ~(size_t)255;
        return p;
    };
    // R1: Hraw8 (67.1 MB); dead after k_ln -> pm/ps/pt alias it
    unsigned char* Hraw8 = (unsigned char*)alloc((size_t)NROWS * TOTD);
    // R2: pred8 + W1_8 live through gemm1; dead after -> H8 overwrites whole region
    unsigned char* R2    = (unsigned char*)alloc((size_t)NROWS * TOTD);
    unsigned char* W2_8  = (unsigned char*)alloc((size_t)TOTD * TOTD);
    unsigned short* LSTb = (unsigned short*)alloc((size_t)SIN * SIN * 2);
    // total ~144.8 MB

    unsigned char* pred8 = R2;
    unsigned char* W1_8  = R2 + (size_t)NROWS * PD;     // 16.8 MB offset (256-aligned)
    unsigned char* H8    = R2;
    float* pm_ = (float*)Hraw8;
    float* ps_ = pm_ + (size_t)32 * NROWS;
    float* pt_ = ps_ + (size_t)32 * NROWS;

    hipMemsetAsync(d_out, 0, 2 * sizeof(float), stream);

    k_cvt8<<<NROWS * PD / 8 / 256, 256, 0, stream>>>(predictor, pred8, 1.f, NROWS * PD / 8);
    k_cvt8<<<TOTD * PD / 8 / 256, 256, 0, stream>>>(W1, W1_8, 16.f, TOTD * PD / 8);
    k_cvt8<<<TOTD * TOTD / 8 / 256, 256, 0, stream>>>(W2, W2_8, 16.f, TOTD * TOTD / 8);
    k_tb<<<dim3(SIN / 32, SIN / 32), 256, 0, stream>>>(LS, LSTb);

    k_gemm1<<<16 * 256, 256, 0, stream>>>(pred8, W1_8, b1, Hraw8);
    k_ln<<<NROWS, 256, 0, stream>>>(Hraw8, H8, LSTb, cbidx, gamma, beta);
    k_gemm2<<<16 * 256, 256, 0, stream>>>(H8, W2_8, b2, cbidx, pm_, ps_, pt_);
    k_comb<<<NROWS * NCB / 256, 256, 0, stream>>>(pm_, ps_, pt_, cbidx, out);
}

// Round 9
// 674.674 us; speedup vs baseline: 1.3362x; 1.0332x over previous
//
#include <hip/hip_runtime.h>

#define NROWS 32768   // B*T
#define PD    512     // P_DIM
#define NCB   8       // NC
#define CSZ   256     // CS
#define TOTD  2048    // TOT
#define SIN   1792    // SELF_IN / SELF_OUT

typedef float floatx4 __attribute__((ext_vector_type(4)));

__device__ __forceinline__ float bf2f(unsigned int h) {
    return __uint_as_float(h << 16);
}
__device__ __forceinline__ unsigned short f2bf(float f) {
    unsigned int u = __float_as_uint(f);
    u += 0x7FFFu + ((u >> 16) & 1u);
    return (unsigned short)(u >> 16);
}
// f32 -> fp8 e4m3 (single value, RNE, saturating)
__device__ __forceinline__ unsigned char f2fp8(float v) {
    int p = __builtin_amdgcn_cvt_pk_fp8_f32(v, v, 0, false);
    return (unsigned char)(p & 0xFF);
}

// async global->LDS, 16B per lane; LDS dest = wave-uniform base + lane*16
__device__ __forceinline__ void gload16(const unsigned char* g, unsigned char* l) {
    __builtin_amdgcn_global_load_lds(
        (const __attribute__((address_space(1))) void*)g,
        (__attribute__((address_space(3))) void*)l, 16, 0, 0);
}

// ---------------- f32 -> fp8 conversion (8 elems/thread) ----------------
__global__ __launch_bounds__(256) void k_cvt8(const float* __restrict__ in,
                                              unsigned char* __restrict__ out,
                                              float scale, int n8) {
    int i = blockIdx.x * 256 + threadIdx.x;
    if (i >= n8) return;
    float4 a = ((const float4*)in)[2 * i];
    float4 b = ((const float4*)in)[2 * i + 1];
    int p0 = __builtin_amdgcn_cvt_pk_fp8_f32(a.x * scale, a.y * scale, 0, false);
    p0     = __builtin_amdgcn_cvt_pk_fp8_f32(a.z * scale, a.w * scale, p0, true);
    int p1 = __builtin_amdgcn_cvt_pk_fp8_f32(b.x * scale, b.y * scale, 0, false);
    p1     = __builtin_amdgcn_cvt_pk_fp8_f32(b.z * scale, b.w * scale, p1, true);
    int2 o; o.x = p0; o.y = p1;
    ((int2*)out)[i] = o;
}

// -------- transpose linear_self (1792x1792) f32 -> bf16, LSTb[in][out] --------
__global__ __launch_bounds__(256) void k_tb(const float* __restrict__ in,
                                            unsigned short* __restrict__ out) {
    __shared__ float t[32][33];
    int bx = blockIdx.x * 32, by = blockIdx.y * 32;
    int tx = threadIdx.x & 31, ty = threadIdx.x >> 5;
#pragma unroll
    for (int j = 0; j < 32; j += 8)
        t[ty + j][tx] = in[(size_t)(by + ty + j) * SIN + bx + tx];
    __syncthreads();
#pragma unroll
    for (int j = 0; j < 32; j += 8)
        out[(size_t)(bx + ty + j) * SIN + by + tx] = f2bf(t[tx][ty + j]);
}

// LDS layout (per 32-k slab, per wave 1024 B): slot = t*32 + h*16 + m  (16 B slots)
//   t = local 16-row tile (0/1), h = 16-byte k-half, m = row in tile.
// Staged by lane = slot: global row = wave*32 + t*16 + m, k-byte = h*16.
// Fragment read (m=lane&15, q=lane>>4): tile*512 + (q>>1)*256 + m*16 + (q&1)*8
//   -> per-quarter banks (m*4 + (q&1)*2)%32: 2-way max (free), vs 4-way before.

// ---------------- GEMM1 (fp8): Hraw8 = fp8(8 * (pred @ W1^T + b1)) ----------------
__global__ __launch_bounds__(256) void k_gemm1(const unsigned char* __restrict__ A,
                                               const unsigned char* __restrict__ Bw,
                                               const float* __restrict__ bias,
                                               unsigned char* __restrict__ Out) {
    const int K = PD;
    __shared__ __align__(16) unsigned char As[2 * 8192];
    __shared__ __align__(16) unsigned char Bs[2 * 8192];

    const int tid  = threadIdx.x;
    const int lane = tid & 63;
    const int wave = tid >> 6;
    const int wm = (wave >> 1) << 6;
    const int wn = (wave & 1) << 6;
    const int bid  = blockIdx.x;
    const int row0 = (bid & 255) << 7;
    const int col0 = (bid >> 8) << 7;

    floatx4 acc[4][4] = {};

    // staging address (separate-halves layout)
    const int srow = wave * 32 + ((lane >> 5) << 4) + (lane & 15);
    const int skb  = ((lane >> 4) & 1) << 4;
    const unsigned char* Ag = A  + (size_t)(row0 + srow) * K + skb;
    const unsigned char* Bg = Bw + (size_t)(col0 + srow) * K + skb;
    unsigned char* Al = As + wave * 1024;
    unsigned char* Bl = Bs + wave * 1024;

    gload16(Ag,      Al);
    gload16(Ag + 32, Al + 4096);
    gload16(Bg,      Bl);
    gload16(Bg + 32, Bl + 4096);

    const int fo = ((lane >> 5) << 8) + ((lane & 15) << 4) + (((lane >> 4) & 1) << 3);

    const int NI = K / 64;   // 8
    for (int i = 0; i < NI; ++i) {
        const int cur = (i & 1) << 13;
        __syncthreads();                 // drains only THIS iter's loads
        if (i + 1 < NI) {
            const int nb = ((i + 1) & 1) << 13;
            const int k0 = (i + 1) * 64;
            gload16(Ag + k0,      Al + nb);
            gload16(Ag + k0 + 32, Al + nb + 4096);
            gload16(Bg + k0,      Bl + nb);
            gload16(Bg + k0 + 32, Bl + nb + 4096);
        }
#pragma unroll
        for (int s = 0; s < 2; ++s) {
            const unsigned char* Ab = As + cur + s * 4096 + fo;
            const unsigned char* Bb = Bs + cur + s * 4096 + fo;
            long af[4], bfv[4];
#pragma unroll
            for (int mt = 0; mt < 4; ++mt) af[mt]  = *(const long*)(Ab + ((wm >> 4) + mt) * 512);
#pragma unroll
            for (int nt = 0; nt < 4; ++nt) bfv[nt] = *(const long*)(Bb + ((wn >> 4) + nt) * 512);
#pragma unroll
            for (int mt = 0; mt < 4; ++mt)
#pragma unroll
                for (int nt = 0; nt < 4; ++nt)
                    acc[mt][nt] = __builtin_amdgcn_mfma_f32_16x16x32_fp8_fp8(af[mt], bfv[nt], acc[mt][nt], 0, 0, 0);
        }
    }

    // epilogue: hidden = acc/16 + b1; store fp8(8*hidden)
#pragma unroll
    for (int mt = 0; mt < 4; ++mt) {
        const int rowb = row0 + wm + mt * 16 + ((lane >> 4) << 2);
#pragma unroll
        for (int nt = 0; nt < 4; ++nt) {
            const int col = col0 + wn + nt * 16 + (lane & 15);
            const float bcol = bias[col];
#pragma unroll
            for (int r = 0; r < 4; ++r) {
                float h = acc[mt][nt][r] * 0.0625f + bcol;
                Out[(size_t)(rowb + r) * TOTD + col] = f2fp8(h * 8.f);
            }
        }
    }
}

// -------- fused: self-gather + relu + LayerNorm; fp8 in (x8) -> fp8 out (x8) --------
__global__ __launch_bounds__(256) void k_ln(const unsigned char* __restrict__ Hraw8,
                                            unsigned char* __restrict__ H8,
                                            const unsigned short* __restrict__ LSTb,
                                            const int* __restrict__ idx,
                                            const float* __restrict__ gamma,
                                            const float* __restrict__ beta) {
    const int row = blockIdx.x;
    const int tid = threadIdx.x;
    __shared__ int sidx[8];
    __shared__ float ws4[4], wss4[4];
    if (tid < 8) sidx[tid] = idx[(size_t)row * NCB + tid];

    uint2 w = ((const uint2*)(Hraw8 + (size_t)row * TOTD))[tid];
    float x[8];
    x[0] = __builtin_amdgcn_cvt_f32_fp8(w.x, 0) * 0.125f;
    x[1] = __builtin_amdgcn_cvt_f32_fp8(w.x, 1) * 0.125f;
    x[2] = __builtin_amdgcn_cvt_f32_fp8(w.x, 2) * 0.125f;
    x[3] = __builtin_amdgcn_cvt_f32_fp8(w.x, 3) * 0.125f;
    x[4] = __builtin_amdgcn_cvt_f32_fp8(w.y, 0) * 0.125f;
    x[5] = __builtin_amdgcn_cvt_f32_fp8(w.y, 1) * 0.125f;
    x[6] = __builtin_amdgcn_cvt_f32_fp8(w.y, 2) * 0.125f;
    x[7] = __builtin_amdgcn_cvt_f32_fp8(w.y, 3) * 0.125f;
    __syncthreads();

    const int gt = tid >> 5;
#pragma unroll
    for (int c = 0; c < 7; ++c) {
        if (c < gt) {
            int ic = sidx[c];
            if (ic >= 0) {
                uint4 v = *(const uint4*)(LSTb + (size_t)(c * CSZ + ic) * SIN + (tid * 8 - CSZ));
                x[0] += bf2f(v.x & 0xFFFF); x[1] += bf2f(v.x >> 16);
                x[2] += bf2f(v.y & 0xFFFF); x[3] += bf2f(v.y >> 16);
                x[4] += bf2f(v.z & 0xFFFF); x[5] += bf2f(v.z >> 16);
                x[6] += bf2f(v.w & 0xFFFF); x[7] += bf2f(v.w >> 16);
            }
        }
    }
#pragma unroll
    for (int e = 0; e < 8; ++e) x[e] = fmaxf(x[e], 0.f);

    float s = 0.f, ss = 0.f;
#pragma unroll
    for (int e = 0; e < 8; ++e) { s += x[e]; ss += x[e] * x[e]; }
#pragma unroll
    for (int o = 32; o; o >>= 1) { s += __shfl_xor(s, o); ss += __shfl_xor(ss, o); }
    if ((tid & 63) == 0) { ws4[tid >> 6] = s; wss4[tid >> 6] = ss; }
    __syncthreads();
    s  = ws4[0] + ws4[1] + ws4[2] + ws4[3];
    ss = wss4[0] + wss4[1] + wss4[2] + wss4[3];
    const float mu = s * (1.f / TOTD);
    const float var = ss * (1.f / TOTD) - mu * mu;
    const float rstd = rsqrtf(var + 1e-5f);
    float y[8];
#pragma unroll
    for (int e = 0; e < 8; ++e) {
        int col = tid * 8 + e;
        y[e] = ((x[e] - mu) * rstd * gamma[col] + beta[col]) * 8.f;   // H scale 8
    }
    int p0 = __builtin_amdgcn_cvt_pk_fp8_f32(y[0], y[1], 0, false);
    p0     = __builtin_amdgcn_cvt_pk_fp8_f32(y[2], y[3], p0, true);
    int p1 = __builtin_amdgcn_cvt_pk_fp8_f32(y[4], y[5], 0, false);
    p1     = __builtin_amdgcn_cvt_pk_fp8_f32(y[6], y[7], p1, true);
    int2 o; o.x = p0; o.y = p1;
    ((int2*)(H8 + (size_t)row * TOTD))[tid] = o;
}

// ------- GEMM2 (fp8): 128x128 tile, dbuf pipeline + per-row partial-softmax epilogue -------
__global__ __launch_bounds__(256) void k_gemm2(const unsigned char* __restrict__ H,
                                               const unsigned char* __restrict__ W2,
                                               const float* __restrict__ b2,
                                               const int* __restrict__ idx,
                                               float* __restrict__ pm_,
                                               float* __restrict__ ps_,
                                               float* __restrict__ pt_) {
    const int K = TOTD;
    __shared__ __align__(16) unsigned char As[2 * 8192];
    __shared__ __align__(16) unsigned char Bs[2 * 8192];
    __shared__ int tidx[128];

    const int tid  = threadIdx.x;
    const int lane = tid & 63;
    const int wave = tid >> 6;
    const int wm = (wave >> 1) << 6;
    const int wn = (wave & 1) << 6;
    const int bid  = blockIdx.x;
    const int row0 = (bid & 255) << 7;
    const int col0 = (bid >> 8) << 7;
    const int g    = col0 >> 8;

    floatx4 acc[4][4] = {};

    const int srow = wave * 32 + ((lane >> 5) << 4) + (lane & 15);
    const int skb  = ((lane >> 4) & 1) << 4;
    const unsigned char* Ag = H  + (size_t)(row0 + srow) * K + skb;
    const unsigned char* Bg = W2 + (size_t)(col0 + srow) * K + skb;
    unsigned char* Al = As + wave * 1024;
    unsigned char* Bl = Bs + wave * 1024;

    if (tid < 128) tidx[tid] = idx[(size_t)(row0 + tid) * NCB + g];

    gload16(Ag,      Al);
    gload16(Ag + 32, Al + 4096);
    gload16(Bg,      Bl);
    gload16(Bg + 32, Bl + 4096);

    const int fo = ((lane >> 5) << 8) + ((lane & 15) << 4) + (((lane >> 4) & 1) << 3);

    const int NI = K / 64;   // 32
    for (int i = 0; i < NI; ++i) {
        const int cur = (i & 1) << 13;
        __syncthreads();
        if (i + 1 < NI) {
            const int nb = ((i + 1) & 1) << 13;
            const int k0 = (i + 1) * 64;
            gload16(Ag + k0,      Al + nb);
            gload16(Ag + k0 + 32, Al + nb + 4096);
            gload16(Bg + k0,      Bl + nb);
            gload16(Bg + k0 + 32, Bl + nb + 4096);
        }
#pragma unroll
        for (int s = 0; s < 2; ++s) {
            const unsigned char* Ab = As + cur + s * 4096 + fo;
            const unsigned char* Bb = Bs + cur + s * 4096 + fo;
            long af[4], bfv[4];
#pragma unroll
            for (int mt = 0; mt < 4; ++mt) af[mt]  = *(const long*)(Ab + ((wm >> 4) + mt) * 512);
#pragma unroll
            for (int nt = 0; nt < 4; ++nt) bfv[nt] = *(const long*)(Bb + ((wn >> 4) + nt) * 512);
#pragma unroll
            for (int mt = 0; mt < 4; ++mt)
#pragma unroll
                for (int nt = 0; nt < 4; ++nt)
                    acc[mt][nt] = __builtin_amdgcn_mfma_f32_16x16x32_fp8_fp8(af[mt], bfv[nt], acc[mt][nt], 0, 0, 0);
        }
    }

    // ---- epilogue: per-row partials over this wave's 64-col window ----
    const int rl = (lane >> 4) << 2;
    const int cl = lane & 15;
    const int slot = (col0 + wn) >> 6;   // 0..31
    const int coff = (col0 & 255) + wn;
    float bcol[4];
#pragma unroll
    for (int nt = 0; nt < 4; ++nt) bcol[nt] = b2[col0 + wn + nt * 16 + cl];

#pragma unroll
    for (int mt = 0; mt < 4; ++mt) {
#pragma unroll
        for (int r = 0; r < 4; ++r) {
            const int lrow = wm + mt * 16 + rl + r;
            const int ic   = tidx[lrow];
            const int tloc = ic - coff;
            float v[4];
            float mm = -3.4e38f, tv = 0.f;
#pragma unroll
            for (int nt = 0; nt < 4; ++nt) {
                v[nt] = acc[mt][nt][r] * 0.0078125f + bcol[nt];
                mm = fmaxf(mm, v[nt]);
                if (ic >= 0 && (nt * 16 + cl) == tloc) tv += v[nt];
            }
#pragma unroll
            for (int o = 1; o < 16; o <<= 1) mm = fmaxf(mm, __shfl_xor(mm, o));
            float sv = __expf(v[0] - mm) + __expf(v[1] - mm) + __expf(v[2] - mm) + __expf(v[3] - mm);
#pragma unroll
            for (int o = 1; o < 16; o <<= 1) { sv += __shfl_xor(sv, o); tv += __shfl_xor(tv, o); }
            if (cl == 0) {
                const int row = row0 + lrow;
                pm_[(size_t)slot * NROWS + row] = mm;
                ps_[(size_t)slot * NROWS + row] = sv;
                pt_[(size_t)slot * NROWS + row] = tv;
            }
        }
    }
}

// ------- combine: merge 4 slots per (row, group), accumulate logprob + count -------
__global__ __launch_bounds__(256) void k_comb(const float* __restrict__ pm_,
                                              const float* __restrict__ ps_,
                                              const float* __restrict__ pt_,
                                              const int* __restrict__ idx,
                                              float* __restrict__ out) {
    const int i   = blockIdx.x * 256 + threadIdx.x;
    const int row = i & (NROWS - 1);
    const int g   = i >> 15;
    const int ic  = idx[(size_t)row * NCB + g];
    float lp = 0.f, cnt = 0.f;
    if (ic >= 0) {
        const size_t b = (size_t)(g * 4) * NROWS + row;
        float m0 = pm_[b], m1 = pm_[b + NROWS], m2 = pm_[b + 2 * NROWS], m3 = pm_[b + 3 * NROWS];
        float mm = fmaxf(fmaxf(m0, m1), fmaxf(m2, m3));
        float Z = ps_[b] * __expf(m0 - mm) + ps_[b + NROWS] * __expf(m1 - mm)
                + ps_[b + 2 * NROWS] * __expf(m2 - mm) + ps_[b + 3 * NROWS] * __expf(m3 - mm);
        float t = pt_[b] + pt_[b + NROWS] + pt_[b + 2 * NROWS] + pt_[b + 3 * NROWS];
        lp = t - (mm + __logf(Z));
        cnt = 1.f;
    }
#pragma unroll
    for (int o = 1; o < 64; o <<= 1) { lp += __shfl_xor(lp, o); cnt += __shfl_xor(cnt, o); }
    __shared__ float wred[8];
    const int lane = threadIdx.x & 63, wave = threadIdx.x >> 6;
    if (lane == 0) { wred[wave] = lp; wred[4 + wave] = cnt; }
    __syncthreads();
    if (threadIdx.x == 0) {
        atomicAdd(&out[0], wred[0] + wred[1] + wred[2] + wred[3]);
        atomicAdd(&out[1], wred[4] + wred[5] + wred[6] + wred[7]);
    }
}

extern "C" void kernel_launch(void* const* d_in, const int* in_sizes, int n_in,
                              void* d_out, int out_size, void* d_ws, size_t ws_size,
                              hipStream_t stream) {
    const float* predictor = (const float*)d_in[0];
    const int*   cbidx     = (const int*)d_in[1];
    const float* W1        = (const float*)d_in[2];
    const float* b1        = (const float*)d_in[3];
    const float* LS        = (const float*)d_in[4];
    const float* gamma     = (const float*)d_in[5];
    const float* beta      = (const float*)d_in[6];
    const float* W2        = (const float*)d_in[7];
    const float* b2        = (const float*)d_in[8];
    float* out = (float*)d_out;

    char* ws = (char*)d_ws;
    size_t off = 0;
    auto alloc = [&](size_t bytes) {
        char* p = ws + off;
        off += (bytes + 255) & ~(size_t)255;
        return p;
    };
    unsigned char* Hraw8 = (unsigned char*)alloc((size_t)NROWS * TOTD);   // dead after k_ln -> pm/ps/pt alias
    unsigned char* R2    = (unsigned char*)alloc((size_t)NROWS * TOTD);   // pred8+W1_8, then H8
    unsigned char* W2_8  = (unsigned char*)alloc((size_t)TOTD * TOTD);
    unsigned short* LSTb = (unsigned short*)alloc((size_t)SIN * SIN * 2);

    unsigned char* pred8 = R2;
    unsigned char* W1_8  = R2 + (size_t)NROWS * PD;
    unsigned char* H8    = R2;
    float* pm_ = (float*)Hraw8;
    float* ps_ = pm_ + (size_t)32 * NROWS;
    float* pt_ = ps_ + (size_t)32 * NROWS;

    hipMemsetAsync(d_out, 0, 2 * sizeof(float), stream);

    k_cvt8<<<NROWS * PD / 8 / 256, 256, 0, stream>>>(predictor, pred8, 1.f, NROWS * PD / 8);
    k_cvt8<<<TOTD * PD / 8 / 256, 256, 0, stream>>>(W1, W1_8, 16.f, TOTD * PD / 8);
    k_cvt8<<<TOTD * TOTD / 8 / 256, 256, 0, stream>>>(W2, W2_8, 16.f, TOTD * TOTD / 8);
    k_tb<<<dim3(SIN / 32, SIN / 32), 256, 0, stream>>>(LS, LSTb);

    k_gemm1<<<16 * 256, 256, 0, stream>>>(pred8, W1_8, b1, Hraw8);
    k_ln<<<NROWS, 256, 0, stream>>>(Hraw8, H8, LSTb, cbidx, gamma, beta);
    k_gemm2<<<16 * 256, 256, 0, stream>>>(H8, W2_8, b2, cbidx, pm_, ps_, pt_);
    k_comb<<<NROWS * NCB / 256, 256, 0, stream>>>(pm_, ps_, pt_, cbidx, out);
}

// Round 10
// 652.102 us; speedup vs baseline: 1.3825x; 1.0346x over previous
//
#include <hip/hip_runtime.h>

#define NROWS 32768   // B*T
#define PD    512     // P_DIM
#define NCB   8       // NC
#define CSZ   256     // CS
#define TOTD  2048    // TOT
#define SIN   1792    // SELF_IN / SELF_OUT

typedef float floatx4 __attribute__((ext_vector_type(4)));

__device__ __forceinline__ float bf2f(unsigned int h) {
    return __uint_as_float(h << 16);
}
__device__ __forceinline__ unsigned short f2bf(float f) {
    unsigned int u = __float_as_uint(f);
    u += 0x7FFFu + ((u >> 16) & 1u);
    return (unsigned short)(u >> 16);
}
// f32 -> fp8 e4m3 (single value, RNE, saturating)
__device__ __forceinline__ unsigned char f2fp8(float v) {
    int p = __builtin_amdgcn_cvt_pk_fp8_f32(v, v, 0, false);
    return (unsigned char)(p & 0xFF);
}

// async global->LDS, 16B per lane; LDS dest = wave-uniform base + lane*16
__device__ __forceinline__ void gload16(const unsigned char* g, unsigned char* l) {
    __builtin_amdgcn_global_load_lds(
        (const __attribute__((address_space(1))) void*)g,
        (__attribute__((address_space(3))) void*)l, 16, 0, 0);
}

// ---------------- f32 -> fp8 conversion (8 elems/thread) ----------------
__global__ __launch_bounds__(256) void k_cvt8(const float* __restrict__ in,
                                              unsigned char* __restrict__ out,
                                              float scale, int n8) {
    int i = blockIdx.x * 256 + threadIdx.x;
    if (i >= n8) return;
    float4 a = ((const float4*)in)[2 * i];
    float4 b = ((const float4*)in)[2 * i + 1];
    int p0 = __builtin_amdgcn_cvt_pk_fp8_f32(a.x * scale, a.y * scale, 0, false);
    p0     = __builtin_amdgcn_cvt_pk_fp8_f32(a.z * scale, a.w * scale, p0, true);
    int p1 = __builtin_amdgcn_cvt_pk_fp8_f32(b.x * scale, b.y * scale, 0, false);
    p1     = __builtin_amdgcn_cvt_pk_fp8_f32(b.z * scale, b.w * scale, p1, true);
    int2 o; o.x = p0; o.y = p1;
    ((int2*)out)[i] = o;
}

// -------- transpose linear_self (1792x1792) f32 -> bf16, LSTb[in][out] --------
__global__ __launch_bounds__(256) void k_tb(const float* __restrict__ in,
                                            unsigned short* __restrict__ out) {
    __shared__ float t[32][33];
    int bx = blockIdx.x * 32, by = blockIdx.y * 32;
    int tx = threadIdx.x & 31, ty = threadIdx.x >> 5;
#pragma unroll
    for (int j = 0; j < 32; j += 8)
        t[ty + j][tx] = in[(size_t)(by + ty + j) * SIN + bx + tx];
    __syncthreads();
#pragma unroll
    for (int j = 0; j < 32; j += 8)
        out[(size_t)(bx + ty + j) * SIN + by + tx] = f2bf(t[tx][ty + j]);
}

// LDS layout per 32-k slab per wave (1024 B): slot = t*32 + h*16 + m (16 B slots)
// Pipeline: TRIPLE buffer; loads for buf i issued at iter i-2; waited with
// vmcnt(4) (own newest prefetch stays in flight across the raw s_barrier).

// ---------------- GEMM1 (fp8): Hraw8 = fp8(8 * (pred @ W1^T + b1)) ----------------
__global__ __launch_bounds__(256) void k_gemm1(const unsigned char* __restrict__ A,
                                               const unsigned char* __restrict__ Bw,
                                               const float* __restrict__ bias,
                                               unsigned char* __restrict__ Out) {
    const int K = PD;
    __shared__ __align__(16) unsigned char As[3 * 8192];
    __shared__ __align__(16) unsigned char Bs[3 * 8192];

    const int tid  = threadIdx.x;
    const int lane = tid & 63;
    const int wave = tid >> 6;
    const int wm = (wave >> 1) << 6;
    const int wn = (wave & 1) << 6;
    const int bid  = blockIdx.x;
    const int row0 = (bid & 255) << 7;
    const int col0 = (bid >> 8) << 7;

    floatx4 acc[4][4] = {};

    const int srow = wave * 32 + ((lane >> 5) << 4) + (lane & 15);
    const int skb  = ((lane >> 4) & 1) << 4;
    const unsigned char* Ag = A  + (size_t)(row0 + srow) * K + skb;
    const unsigned char* Bg = Bw + (size_t)(col0 + srow) * K + skb;
    unsigned char* Al = As + wave * 1024;
    unsigned char* Bl = Bs + wave * 1024;

    // prologue: stage buffers 0 and 1
    gload16(Ag,            Al);
    gload16(Ag + 32,       Al + 4096);
    gload16(Bg,            Bl);
    gload16(Bg + 32,       Bl + 4096);
    gload16(Ag + 64,       Al + 8192);
    gload16(Ag + 96,       Al + 8192 + 4096);
    gload16(Bg + 64,       Bl + 8192);
    gload16(Bg + 96,       Bl + 8192 + 4096);

    const int fo = ((lane >> 5) << 8) + ((lane & 15) << 4) + (((lane >> 4) & 1) << 3);

    auto compute = [&](int cb) {
        const int cur = cb * 8192;
#pragma unroll
        for (int s = 0; s < 2; ++s) {
            const unsigned char* Ab = As + cur + s * 4096 + fo;
            const unsigned char* Bb = Bs + cur + s * 4096 + fo;
            long af[4], bfv[4];
#pragma unroll
            for (int mt = 0; mt < 4; ++mt) af[mt]  = *(const long*)(Ab + ((wm >> 4) + mt) * 512);
#pragma unroll
            for (int nt = 0; nt < 4; ++nt) bfv[nt] = *(const long*)(Bb + ((wn >> 4) + nt) * 512);
#pragma unroll
            for (int mt = 0; mt < 4; ++mt)
#pragma unroll
                for (int nt = 0; nt < 4; ++nt)
                    acc[mt][nt] = __builtin_amdgcn_mfma_f32_16x16x32_fp8_fp8(af[mt], bfv[nt], acc[mt][nt], 0, 0, 0);
        }
    };

    const int NI = K / 64;   // 8
    int cb = 0, nb = 2;
    for (int i = 0; i < NI - 1; ++i) {
        asm volatile("s_waitcnt vmcnt(4)" ::: "memory");
        asm volatile("s_barrier" ::: "memory");
        if (i + 2 < NI) {
            const int k0 = (i + 2) * 64;
            gload16(Ag + k0,      Al + nb * 8192);
            gload16(Ag + k0 + 32, Al + nb * 8192 + 4096);
            gload16(Bg + k0,      Bl + nb * 8192);
            gload16(Bg + k0 + 32, Bl + nb * 8192 + 4096);
        }
        compute(cb);
        cb = (cb + 1 == 3) ? 0 : cb + 1;
        nb = (nb + 1 == 3) ? 0 : nb + 1;
    }
    asm volatile("s_waitcnt vmcnt(0)" ::: "memory");
    asm volatile("s_barrier" ::: "memory");
    compute(cb);

    // epilogue: hidden = acc/16 + b1; store fp8(8*hidden)
#pragma unroll
    for (int mt = 0; mt < 4; ++mt) {
        const int rowb = row0 + wm + mt * 16 + ((lane >> 4) << 2);
#pragma unroll
        for (int nt = 0; nt < 4; ++nt) {
            const int col = col0 + wn + nt * 16 + (lane & 15);
            const float bcol = bias[col];
#pragma unroll
            for (int r = 0; r < 4; ++r) {
                float h = acc[mt][nt][r] * 0.0625f + bcol;
                Out[(size_t)(rowb + r) * TOTD + col] = f2fp8(h * 8.f);
            }
        }
    }
}

// -------- fused: self-gather + relu + LayerNorm; fp8 in (x8) -> fp8 out (x8) --------
__global__ __launch_bounds__(256) void k_ln(const unsigned char* __restrict__ Hraw8,
                                            unsigned char* __restrict__ H8,
                                            const unsigned short* __restrict__ LSTb,
                                            const int* __restrict__ idx,
                                            const float* __restrict__ gamma,
                                            const float* __restrict__ beta) {
    const int row = blockIdx.x;
    const int tid = threadIdx.x;
    __shared__ int sidx[8];
    __shared__ float ws4[4], wss4[4];
    if (tid < 8) sidx[tid] = idx[(size_t)row * NCB + tid];

    uint2 w = ((const uint2*)(Hraw8 + (size_t)row * TOTD))[tid];
    float x[8];
    x[0] = __builtin_amdgcn_cvt_f32_fp8(w.x, 0) * 0.125f;
    x[1] = __builtin_amdgcn_cvt_f32_fp8(w.x, 1) * 0.125f;
    x[2] = __builtin_amdgcn_cvt_f32_fp8(w.x, 2) * 0.125f;
    x[3] = __builtin_amdgcn_cvt_f32_fp8(w.x, 3) * 0.125f;
    x[4] = __builtin_amdgcn_cvt_f32_fp8(w.y, 0) * 0.125f;
    x[5] = __builtin_amdgcn_cvt_f32_fp8(w.y, 1) * 0.125f;
    x[6] = __builtin_amdgcn_cvt_f32_fp8(w.y, 2) * 0.125f;
    x[7] = __builtin_amdgcn_cvt_f32_fp8(w.y, 3) * 0.125f;
    __syncthreads();

    const int gt = tid >> 5;
#pragma unroll
    for (int c = 0; c < 7; ++c) {
        if (c < gt) {
            int ic = sidx[c];
            if (ic >= 0) {
                uint4 v = *(const uint4*)(LSTb + (size_t)(c * CSZ + ic) * SIN + (tid * 8 - CSZ));
                x[0] += bf2f(v.x & 0xFFFF); x[1] += bf2f(v.x >> 16);
                x[2] += bf2f(v.y & 0xFFFF); x[3] += bf2f(v.y >> 16);
                x[4] += bf2f(v.z & 0xFFFF); x[5] += bf2f(v.z >> 16);
                x[6] += bf2f(v.w & 0xFFFF); x[7] += bf2f(v.w >> 16);
            }
        }
    }
#pragma unroll
    for (int e = 0; e < 8; ++e) x[e] = fmaxf(x[e], 0.f);

    float s = 0.f, ss = 0.f;
#pragma unroll
    for (int e = 0; e < 8; ++e) { s += x[e]; ss += x[e] * x[e]; }
#pragma unroll
    for (int o = 32; o; o >>= 1) { s += __shfl_xor(s, o); ss += __shfl_xor(ss, o); }
    if ((tid & 63) == 0) { ws4[tid >> 6] = s; wss4[tid >> 6] = ss; }
    __syncthreads();
    s  = ws4[0] + ws4[1] + ws4[2] + ws4[3];
    ss = wss4[0] + wss4[1] + wss4[2] + wss4[3];
    const float mu = s * (1.f / TOTD);
    const float var = ss * (1.f / TOTD) - mu * mu;
    const float rstd = rsqrtf(var + 1e-5f);
    float y[8];
#pragma unroll
    for (int e = 0; e < 8; ++e) {
        int col = tid * 8 + e;
        y[e] = ((x[e] - mu) * rstd * gamma[col] + beta[col]) * 8.f;   // H scale 8
    }
    int p0 = __builtin_amdgcn_cvt_pk_fp8_f32(y[0], y[1], 0, false);
    p0     = __builtin_amdgcn_cvt_pk_fp8_f32(y[2], y[3], p0, true);
    int p1 = __builtin_amdgcn_cvt_pk_fp8_f32(y[4], y[5], 0, false);
    p1     = __builtin_amdgcn_cvt_pk_fp8_f32(y[6], y[7], p1, true);
    int2 o; o.x = p0; o.y = p1;
    ((int2*)(H8 + (size_t)row * TOTD))[tid] = o;
}

// ------- GEMM2 (fp8): 128x128 tile, triple-buffer pipeline + partial-softmax epilogue -------
__global__ __launch_bounds__(256) void k_gemm2(const unsigned char* __restrict__ H,
                                               const unsigned char* __restrict__ W2,
                                               const float* __restrict__ b2,
                                               const int* __restrict__ idx,
                                               float* __restrict__ pm_,
                                               float* __restrict__ ps_,
                                               float* __restrict__ pt_) {
    const int K = TOTD;
    __shared__ __align__(16) unsigned char As[3 * 8192];
    __shared__ __align__(16) unsigned char Bs[3 * 8192];
    __shared__ int tidx[128];

    const int tid  = threadIdx.x;
    const int lane = tid & 63;
    const int wave = tid >> 6;
    const int wm = (wave >> 1) << 6;
    const int wn = (wave & 1) << 6;
    const int bid  = blockIdx.x;
    const int row0 = (bid & 255) << 7;
    const int col0 = (bid >> 8) << 7;
    const int g    = col0 >> 8;

    floatx4 acc[4][4] = {};

    const int srow = wave * 32 + ((lane >> 5) << 4) + (lane & 15);
    const int skb  = ((lane >> 4) & 1) << 4;
    const unsigned char* Ag = H  + (size_t)(row0 + srow) * K + skb;
    const unsigned char* Bg = W2 + (size_t)(col0 + srow) * K + skb;
    unsigned char* Al = As + wave * 1024;
    unsigned char* Bl = Bs + wave * 1024;

    if (tid < 128) tidx[tid] = idx[(size_t)(row0 + tid) * NCB + g];

    gload16(Ag,            Al);
    gload16(Ag + 32,       Al + 4096);
    gload16(Bg,            Bl);
    gload16(Bg + 32,       Bl + 4096);
    gload16(Ag + 64,       Al + 8192);
    gload16(Ag + 96,       Al + 8192 + 4096);
    gload16(Bg + 64,       Bl + 8192);
    gload16(Bg + 96,       Bl + 8192 + 4096);

    const int fo = ((lane >> 5) << 8) + ((lane & 15) << 4) + (((lane >> 4) & 1) << 3);

    auto compute = [&](int cbuf) {
        const int cur = cbuf * 8192;
#pragma unroll
        for (int s = 0; s < 2; ++s) {
            const unsigned char* Ab = As + cur + s * 4096 + fo;
            const unsigned char* Bb = Bs + cur + s * 4096 + fo;
            long af[4], bfv[4];
#pragma unroll
            for (int mt = 0; mt < 4; ++mt) af[mt]  = *(const long*)(Ab + ((wm >> 4) + mt) * 512);
#pragma unroll
            for (int nt = 0; nt < 4; ++nt) bfv[nt] = *(const long*)(Bb + ((wn >> 4) + nt) * 512);
#pragma unroll
            for (int mt = 0; mt < 4; ++mt)
#pragma unroll
                for (int nt = 0; nt < 4; ++nt)
                    acc[mt][nt] = __builtin_amdgcn_mfma_f32_16x16x32_fp8_fp8(af[mt], bfv[nt], acc[mt][nt], 0, 0, 0);
        }
    };

    const int NI = K / 64;   // 32
    int cb = 0, nb = 2;
    for (int i = 0; i < NI - 1; ++i) {
        asm volatile("s_waitcnt vmcnt(4)" ::: "memory");
        asm volatile("s_barrier" ::: "memory");
        if (i + 2 < NI) {
            const int k0 = (i + 2) * 64;
            gload16(Ag + k0,      Al + nb * 8192);
            gload16(Ag + k0 + 32, Al + nb * 8192 + 4096);
            gload16(Bg + k0,      Bl + nb * 8192);
            gload16(Bg + k0 + 32, Bl + nb * 8192 + 4096);
        }
        compute(cb);
        cb = (cb + 1 == 3) ? 0 : cb + 1;
        nb = (nb + 1 == 3) ? 0 : nb + 1;
    }
    asm volatile("s_waitcnt vmcnt(0)" ::: "memory");
    asm volatile("s_barrier" ::: "memory");
    compute(cb);

    // ---- epilogue: per-row partials over this wave's 64-col window ----
    const int rl = (lane >> 4) << 2;
    const int cl = lane & 15;
    const int slot = (col0 + wn) >> 6;   // 0..31
    const int coff = (col0 & 255) + wn;
    float bcol[4];
#pragma unroll
    for (int nt = 0; nt < 4; ++nt) bcol[nt] = b2[col0 + wn + nt * 16 + cl];

#pragma unroll
    for (int mt = 0; mt < 4; ++mt) {
#pragma unroll
        for (int r = 0; r < 4; ++r) {
            const int lrow = wm + mt * 16 + rl + r;
            const int ic   = tidx[lrow];
            const int tloc = ic - coff;
            float v[4];
            float mm = -3.4e38f, tv = 0.f;
#pragma unroll
            for (int nt = 0; nt < 4; ++nt) {
                v[nt] = acc[mt][nt][r] * 0.0078125f + bcol[nt];
                mm = fmaxf(mm, v[nt]);
                if (ic >= 0 && (nt * 16 + cl) == tloc) tv += v[nt];
            }
#pragma unroll
            for (int o = 1; o < 16; o <<= 1) mm = fmaxf(mm, __shfl_xor(mm, o));
            float sv = __expf(v[0] - mm) + __expf(v[1] - mm) + __expf(v[2] - mm) + __expf(v[3] - mm);
#pragma unroll
            for (int o = 1; o < 16; o <<= 1) { sv += __shfl_xor(sv, o); tv += __shfl_xor(tv, o); }
            if (cl == 0) {
                const int row = row0 + lrow;
                pm_[(size_t)slot * NROWS + row] = mm;
                ps_[(size_t)slot * NROWS + row] = sv;
                pt_[(size_t)slot * NROWS + row] = tv;
            }
        }
    }
}

// ------- combine: merge 4 slots per (row, group), accumulate logprob + count -------
__global__ __launch_bounds__(256) void k_comb(const float* __restrict__ pm_,
                                              const float* __restrict__ ps_,
                                              const float* __restrict__ pt_,
                                              const int* __restrict__ idx,
                                              float* __restrict__ out) {
    const int i   = blockIdx.x * 256 + threadIdx.x;
    const int row = i & (NROWS - 1);
    const int g   = i >> 15;
    const int ic  = idx[(size_t)row * NCB + g];
    float lp = 0.f, cnt = 0.f;
    if (ic >= 0) {
        const size_t b = (size_t)(g * 4) * NROWS + row;
        float m0 = pm_[b], m1 = pm_[b + NROWS], m2 = pm_[b + 2 * NROWS], m3 = pm_[b + 3 * NROWS];
        float mm = fmaxf(fmaxf(m0, m1), fmaxf(m2, m3));
        float Z = ps_[b] * __expf(m0 - mm) + ps_[b + NROWS] * __expf(m1 - mm)
                + ps_[b + 2 * NROWS] * __expf(m2 - mm) + ps_[b + 3 * NROWS] * __expf(m3 - mm);
        float t = pt_[b] + pt_[b + NROWS] + pt_[b + 2 * NROWS] + pt_[b + 3 * NROWS];
        lp = t - (mm + __logf(Z));
        cnt = 1.f;
    }
#pragma unroll
    for (int o = 1; o < 64; o <<= 1) { lp += __shfl_xor(lp, o); cnt += __shfl_xor(cnt, o); }
    __shared__ float wred[8];
    const int lane = threadIdx.x & 63, wave = threadIdx.x >> 6;
    if (lane == 0) { wred[wave] = lp; wred[4 + wave] = cnt; }
    __syncthreads();
    if (threadIdx.x == 0) {
        atomicAdd(&out[0], wred[0] + wred[1] + wred[2] + wred[3]);
        atomicAdd(&out[1], wred[4] + wred[5] + wred[6] + wred[7]);
    }
}

extern "C" void kernel_launch(void* const* d_in, const int* in_sizes, int n_in,
                              void* d_out, int out_size, void* d_ws, size_t ws_size,
                              hipStream_t stream) {
    const float* predictor = (const float*)d_in[0];
    const int*   cbidx     = (const int*)d_in[1];
    const float* W1        = (const float*)d_in[2];
    const float* b1        = (const float*)d_in[3];
    const float* LS        = (const float*)d_in[4];
    const float* gamma     = (const float*)d_in[5];
    const float* beta      = (const float*)d_in[6];
    const float* W2        = (const float*)d_in[7];
    const float* b2        = (const float*)d_in[8];
    float* out = (float*)d_out;

    char* ws = (char*)d_ws;
    size_t off = 0;
    auto alloc = [&](size_t bytes) {
        char* p = ws + off;
        off += (bytes + 255) & ~(size_t)255;
        return p;
    };
    unsigned char* Hraw8 = (unsigned char*)alloc((size_t)NROWS * TOTD);   // dead after k_ln -> pm/ps/pt alias
    unsigned char* R2    = (unsigned char*)alloc((size_t)NROWS * TOTD);   // pred8+W1_8, then H8
    unsigned char* W2_8  = (unsigned char*)alloc((size_t)TOTD * TOTD);
    unsigned short* LSTb = (unsigned short*)alloc((size_t)SIN * SIN * 2);

    unsigned char* pred8 = R2;
    unsigned char* W1_8  = R2 + (size_t)NROWS * PD;
    unsigned char* H8    = R2;
    float* pm_ = (float*)Hraw8;
    float* ps_ = pm_ + (size_t)32 * NROWS;
    float* pt_ = ps_ + (size_t)32 * NROWS;

    hipMemsetAsync(d_out, 0, 2 * sizeof(float), stream);

    k_cvt8<<<NROWS * PD / 8 / 256, 256, 0, stream>>>(predictor, pred8, 1.f, NROWS * PD / 8);
    k_cvt8<<<TOTD * PD / 8 / 256, 256, 0, stream>>>(W1, W1_8, 16.f, TOTD * PD / 8);
    k_cvt8<<<TOTD * TOTD / 8 / 256, 256, 0, stream>>>(W2, W2_8, 16.f, TOTD * TOTD / 8);
    k_tb<<<dim3(SIN / 32, SIN / 32), 256, 0, stream>>>(LS, LSTb);

    k_gemm1<<<16 * 256, 256, 0, stream>>>(pred8, W1_8, b1, Hraw8);
    k_ln<<<NROWS, 256, 0, stream>>>(Hraw8, H8, LSTb, cbidx, gamma, beta);
    k_gemm2<<<16 * 256, 256, 0, stream>>>(H8, W2_8, b2, cbidx, pm_, ps_, pt_);
    k_comb<<<NROWS * NCB / 256, 256, 0, stream>>>(pm_, ps_, pt_, cbidx, out);
}